// Round 5
// baseline (136.387 us; speedup 1.0000x reference)
//
#include <hip/hip_runtime.h>

#define NROWS 512
#define NLAB  16
#define TILE  16
#define GRIDX (NROWS / TILE)      // 32
#define NBLK  (GRIDX * GRIDX)     // 1024
#define NBANK 64                  // banked global accumulators (64 cachelines)

// One dispatch (after a 4.1 KB memset):
//  - each block computes its 16x16 (i,j) tile's 16 label partials and
//    atomicAdds them into acc[blk&63][l] (banked -> low contention).
//  - the LAST block to bump the ticket (acq_rel) inlines the finalize:
//    reduce 64x16 banks, count n_pos, apply weights, write scalar.
// No block ever waits on another block (no spin, no grid barrier).
__global__ __launch_bounds__(256) void auc_onepass(const int* __restrict__ yt,
                                                   const float* __restrict__ yp,
                                                   float* __restrict__ acc,      // [NBANK][NLAB]
                                                   unsigned* __restrict__ ticket,
                                                   float* __restrict__ out) {
    __shared__ float ya[TILE][TILE];       // yp rows of the i-tile
    __shared__ float yb[TILE][TILE];       // yp rows of the j-tile, pre-biased +1
    __shared__ float S_tile[TILE][TILE + 1];
    __shared__ unsigned posA[TILE];
    __shared__ unsigned posB[TILE];
    __shared__ int islast;
    __shared__ float lsum[16][NLAB];
    __shared__ int   lcnt[16][NLAB];
    __shared__ float pl_s[NLAB];
    __shared__ int   pl_c[NLAB];

    const int bx = blockIdx.x;
    const int i0 = (bx >> 5) * TILE;
    const int j0 = (bx & 31) * TILE;
    const int t  = threadIdx.x;
    const int r  = t >> 4;     // 0..15
    const int c  = t & 15;     // 0..15

    // Stage yp rows (coalesced); build per-row pos bitmasks via ballot.
    ya[r][c] = yp[(i0 + r) * NLAB + c];
    yb[r][c] = yp[(j0 + r) * NLAB + c] + 1.0f;
    {
        // each wave holds 4 rows x 16 labels; ballot packs them.
        unsigned long long ba = __ballot(yt[(i0 + r) * NLAB + c] == 1);
        unsigned long long bb = __ballot(yt[(j0 + r) * NLAB + c] == 1);
        if (c == 0) {
            posA[r] = (unsigned)((ba >> ((r & 3) * 16)) & 0xFFFFull);
            posB[r] = (unsigned)((bb >> ((r & 3) * 16)) & 0xFFFFull);
        }
    }
    __syncthreads();

    // S[r][c] = sum_{cc,d} relu(1 - yp[i0+r][cc] + yp[j0+c][d])
    float a[TILE], b[TILE];
    #pragma unroll
    for (int k = 0; k < TILE; ++k) a[k] = ya[r][k];
    #pragma unroll
    for (int k = 0; k < TILE; ++k) b[k] = yb[c][k];

    float S = 0.0f;
    #pragma unroll
    for (int d = 0; d < TILE; ++d) {
        #pragma unroll
        for (int cc = 0; cc < TILE; ++cc) {
            S += fmaxf(b[d] - a[cc], 0.0f);
        }
    }
    S_tile[r][c] = S;
    __syncthreads();

    // Bilinear form per label: thread (l=r, ti=c) masked row-sum, then
    // 4-step shfl_xor reduce over ti; lane ti==0 adds into the banked acc.
    {
        const int l = r, ti = c;
        float rowsum = 0.0f;
        #pragma unroll
        for (int tj = 0; tj < TILE; ++tj) {
            if (((~posB[tj]) >> l) & 1u) rowsum += S_tile[ti][tj];
        }
        float val = ((posA[ti] >> l) & 1u) ? rowsum : 0.0f;
        val += __shfl_xor(val, 1);
        val += __shfl_xor(val, 2);
        val += __shfl_xor(val, 4);
        val += __shfl_xor(val, 8);
        if (ti == 0) atomicAdd(&acc[(bx & (NBANK - 1)) * NLAB + l], val);
    }

    __threadfence();   // order our acc atomics before the ticket bump
    __syncthreads();
    if (t == 0) {
        unsigned old = __hip_atomic_fetch_add(ticket, 1u, __ATOMIC_ACQ_REL,
                                              __HIP_MEMORY_SCOPE_AGENT);
        islast = (old == NBLK - 1) ? 1 : 0;
    }
    __syncthreads();
    if (!islast) return;       // uniform across the block

    // ---- finalize: only the last-finishing block runs this ----
    __threadfence();           // acquire side for non-t0 threads

    const int lab = t & 15;
    const int grp = t >> 4;    // 0..15

    float s = 0.0f;
    #pragma unroll
    for (int g = 0; g < NBANK / 16; ++g) {
        s += __hip_atomic_load(&acc[(grp + 16 * g) * NLAB + lab],
                               __ATOMIC_RELAXED, __HIP_MEMORY_SCOPE_AGENT);
    }
    lsum[grp][lab] = s;

    int cnt = 0;
    for (int k = 0; k < NROWS / 16; ++k) {
        cnt += (yt[(grp + 16 * k) * NLAB + lab] == 1) ? 1 : 0;
    }
    lcnt[grp][lab] = cnt;
    __syncthreads();

    if (t < NLAB) {
        float ps = 0.0f;
        int pc = 0;
        #pragma unroll
        for (int g = 0; g < 16; ++g) {
            ps += lsum[g][t];
            pc += lcnt[g][t];
        }
        pl_s[t] = ps;
        pl_c[t] = pc;
    }
    __syncthreads();

    if (t == 0) {
        double loss = 0.0;
        #pragma unroll
        for (int l = 0; l < NLAB; ++l) {
            const int np_ = pl_c[l];
            const int nn_ = NROWS - np_;   // mn = 1 - mp
            if (np_ > 0 && nn_ > 0) {
                const double prod = (double)np_ * (double)nn_;
                const double denom = prod * prod * (double)(NLAB * NLAB);
                loss += (double)pl_s[l] / denom;
            }
        }
        out[0] = (float)loss;
    }
}

extern "C" void kernel_launch(void* const* d_in, const int* in_sizes, int n_in,
                              void* d_out, int out_size, void* d_ws, size_t ws_size,
                              hipStream_t stream) {
    const int* y_true = (const int*)d_in[0];
    const float* y_pred = (const float*)d_in[1];
    float* out = (float*)d_out;
    float* acc = (float*)d_ws;                         // NBANK*NLAB floats (4 KB)
    unsigned* ticket = (unsigned*)(acc + NBANK * NLAB); // 1 u32

    // Zero accumulators + ticket ourselves (graph-capture-legal async memset);
    // nothing depends on the harness's 0xAA poison semantics.
    hipMemsetAsync(d_ws, 0, NBANK * NLAB * sizeof(float) + sizeof(unsigned), stream);

    auc_onepass<<<NBLK, 256, 0, stream>>>(y_true, y_pred, acc, ticket, out);
}

// Round 6
// 78.421 us; speedup vs baseline: 1.7392x; 1.7392x over previous
//
#include <hip/hip_runtime.h>

#define NROWS 512
#define NLAB  16
#define TILE  16
#define GRIDX (NROWS / TILE)      // 32
#define NBLK  (GRIDX * GRIDX)     // 1024
#define NSLOT (NBLK * NLAB)       // 16384
#define POISON 0xAAAAAAAAu        // harness ws poison; float bits are negative -> never a legit partial

// Single dispatch, zero fences, zero release/acquire ops:
//  - each block computes its 16x16 (i,j) tile's 16 label partials and publishes
//    them with RELAXED agent-scope atomic stores (device-coherent per address,
//    no L2 cache-maintenance). The data doubles as the ready flag: partials are
//    sums of relu >= 0 (sign bit 0), so the 0xAAAAAAAA poison (sign bit 1) is
//    unambiguous "not yet written".
//  - block NBLK-1 (dispatched last) polls all slots with relaxed atomic loads,
//    then reduces, counts n_pos, applies the dynamic weights, writes the scalar.
// Producers never wait on anything. No cross-address ordering is required.
__global__ __launch_bounds__(256) void auc_onepass(const int* __restrict__ yt,
                                                   const float* __restrict__ yp,
                                                   unsigned* __restrict__ partial,  // float bits, [NBLK][NLAB]
                                                   float* __restrict__ out) {
    __shared__ float ya[TILE][TILE];       // yp rows of the i-tile
    __shared__ float yb[TILE][TILE];       // yp rows of the j-tile, pre-biased +1
    __shared__ float S_tile[TILE][TILE + 1];
    __shared__ unsigned posA[TILE];
    __shared__ unsigned posB[TILE];

    const int bx = blockIdx.x;
    const int i0 = (bx >> 5) * TILE;
    const int j0 = (bx & 31) * TILE;
    const int t  = threadIdx.x;
    const int r  = t >> 4;     // 0..15
    const int c  = t & 15;     // 0..15

    // Stage yp rows (coalesced); build per-row pos bitmasks via ballot.
    ya[r][c] = yp[(i0 + r) * NLAB + c];
    yb[r][c] = yp[(j0 + r) * NLAB + c] + 1.0f;
    {
        // each wave holds 4 rows x 16 labels; ballot packs them.
        unsigned long long ba = __ballot(yt[(i0 + r) * NLAB + c] == 1);
        unsigned long long bb = __ballot(yt[(j0 + r) * NLAB + c] == 1);
        if (c == 0) {
            posA[r] = (unsigned)((ba >> ((r & 3) * 16)) & 0xFFFFull);
            posB[r] = (unsigned)((bb >> ((r & 3) * 16)) & 0xFFFFull);
        }
    }
    __syncthreads();

    // S[r][c] = sum_{cc,d} relu(1 - yp[i0+r][cc] + yp[j0+c][d])
    float a[TILE], b[TILE];
    #pragma unroll
    for (int k = 0; k < TILE; ++k) a[k] = ya[r][k];
    #pragma unroll
    for (int k = 0; k < TILE; ++k) b[k] = yb[c][k];

    float S = 0.0f;
    #pragma unroll
    for (int d = 0; d < TILE; ++d) {
        #pragma unroll
        for (int cc = 0; cc < TILE; ++cc) {
            S += fmaxf(b[d] - a[cc], 0.0f);
        }
    }
    S_tile[r][c] = S;
    __syncthreads();

    // Bilinear form per label: thread (l=r, ti=c) masked row-sum, then
    // 4-step shfl_xor reduce over ti; lane ti==0 publishes the partial.
    {
        const int l = r, ti = c;
        float rowsum = 0.0f;
        #pragma unroll
        for (int tj = 0; tj < TILE; ++tj) {
            if (((~posB[tj]) >> l) & 1u) rowsum += S_tile[ti][tj];
        }
        float val = ((posA[ti] >> l) & 1u) ? rowsum : 0.0f;
        val += __shfl_xor(val, 1);
        val += __shfl_xor(val, 2);
        val += __shfl_xor(val, 4);
        val += __shfl_xor(val, 8);
        if (ti == 0) {
            __hip_atomic_store(&partial[bx * NLAB + l], __float_as_uint(val),
                               __ATOMIC_RELAXED, __HIP_MEMORY_SCOPE_AGENT);
        }
    }

    if (bx != NBLK - 1) return;   // producers are done; no waiting anywhere

    // ---- finalizer: last-indexed block only ----
    __shared__ float lsum[16][NLAB];
    __shared__ int   lcnt[16][NLAB];
    __shared__ float pl_s[NLAB];
    __shared__ int   pl_c[NLAB];

    // Thread t owns slots t, t+256, ... (stride 256 ≡ 0 mod 16 -> constant label t&15).
    float s = 0.0f;
    for (int i = t; i < NSLOT; i += 256) {
        unsigned u = __hip_atomic_load(&partial[i], __ATOMIC_RELAXED, __HIP_MEMORY_SCOPE_AGENT);
        while (u == POISON) {
            u = __hip_atomic_load(&partial[i], __ATOMIC_RELAXED, __HIP_MEMORY_SCOPE_AGENT);
        }
        s += __uint_as_float(u);
    }
    lsum[t >> 4][t & 15] = s;

    int cnt = 0;
    for (int k = 0; k < NROWS / 16; ++k) {
        cnt += (yt[((t >> 4) + 16 * k) * NLAB + (t & 15)] == 1) ? 1 : 0;
    }
    lcnt[t >> 4][t & 15] = cnt;
    __syncthreads();

    if (t < NLAB) {
        float ps = 0.0f;
        int pc = 0;
        #pragma unroll
        for (int g = 0; g < 16; ++g) {
            ps += lsum[g][t];
            pc += lcnt[g][t];
        }
        pl_s[t] = ps;
        pl_c[t] = pc;
    }
    __syncthreads();

    if (t == 0) {
        double loss = 0.0;
        #pragma unroll
        for (int l = 0; l < NLAB; ++l) {
            const int np_ = pl_c[l];
            const int nn_ = NROWS - np_;   // mn = 1 - mp
            if (np_ > 0 && nn_ > 0) {
                const double prod = (double)np_ * (double)nn_;
                const double denom = prod * prod * (double)(NLAB * NLAB);
                loss += (double)pl_s[l] / denom;
            }
        }
        out[0] = (float)loss;
    }
}

extern "C" void kernel_launch(void* const* d_in, const int* in_sizes, int n_in,
                              void* d_out, int out_size, void* d_ws, size_t ws_size,
                              hipStream_t stream) {
    const int* y_true = (const int*)d_in[0];
    const float* y_pred = (const float*)d_in[1];
    float* out = (float*)d_out;
    unsigned* partial = (unsigned*)d_ws;   // NSLOT u32 (64 KB), poisoned 0xAA by harness

    auc_onepass<<<NBLK, 256, 0, stream>>>(y_true, y_pred, partial, out);
}

// Round 8
// 65.383 us; speedup vs baseline: 2.0860x; 1.1994x over previous
//
#include <hip/hip_runtime.h>

#define NROWS 512
#define NLAB  16
#define TILE  16
#define GRIDX (NROWS / TILE)      // 32
#define NBLK  (GRIDX * GRIDX)     // 1024

// Dispatch 1: one block per 16x16 tile of (i,j) row pairs.
// No atomics anywhere: S_tile + shfl_xor reduction, plain coalesced store of
// the 16 per-label partials. Visibility comes from the kernel boundary.
__global__ __launch_bounds__(256) void auc_pair(const int* __restrict__ yt,
                                                const float* __restrict__ yp,
                                                float* __restrict__ partial) {
    __shared__ float ya[TILE][TILE];       // yp rows of the i-tile
    __shared__ float yb[TILE][TILE];       // yp rows of the j-tile, pre-biased +1
    __shared__ float S_tile[TILE][TILE + 1];
    __shared__ unsigned posA[TILE];
    __shared__ unsigned posB[TILE];

    const int bx = blockIdx.x;
    const int i0 = (bx >> 5) * TILE;
    const int j0 = (bx & 31) * TILE;
    const int t  = threadIdx.x;
    const int r  = t >> 4;     // 0..15
    const int c  = t & 15;     // 0..15

    // Stage yp rows (coalesced); build per-row pos bitmasks via ballot.
    ya[r][c] = yp[(i0 + r) * NLAB + c];
    yb[r][c] = yp[(j0 + r) * NLAB + c] + 1.0f;
    {
        // each wave holds 4 rows x 16 labels; ballot packs them.
        unsigned long long ba = __ballot(yt[(i0 + r) * NLAB + c] == 1);
        unsigned long long bb = __ballot(yt[(j0 + r) * NLAB + c] == 1);
        if (c == 0) {
            posA[r] = (unsigned)((ba >> ((r & 3) * 16)) & 0xFFFFull);
            posB[r] = (unsigned)((bb >> ((r & 3) * 16)) & 0xFFFFull);
        }
    }
    __syncthreads();

    // S[r][c] = sum_{cc,d} relu(1 - yp[i0+r][cc] + yp[j0+c][d])
    float a[TILE], b[TILE];
    #pragma unroll
    for (int k = 0; k < TILE; ++k) a[k] = ya[r][k];
    #pragma unroll
    for (int k = 0; k < TILE; ++k) b[k] = yb[c][k];

    float S = 0.0f;
    #pragma unroll
    for (int d = 0; d < TILE; ++d) {
        #pragma unroll
        for (int cc = 0; cc < TILE; ++cc) {
            S += fmaxf(b[d] - a[cc], 0.0f);
        }
    }
    S_tile[r][c] = S;
    __syncthreads();

    // Bilinear form per label: thread (l=r, ti=c) masked row-sum, then
    // 4-step shfl_xor reduce over ti; lane ti==0 stores the partial.
    {
        const int l = r, ti = c;
        float rowsum = 0.0f;
        #pragma unroll
        for (int tj = 0; tj < TILE; ++tj) {
            if (((~posB[tj]) >> l) & 1u) rowsum += S_tile[ti][tj];
        }
        float val = ((posA[ti] >> l) & 1u) ? rowsum : 0.0f;
        val += __shfl_xor(val, 1);
        val += __shfl_xor(val, 2);
        val += __shfl_xor(val, 4);
        val += __shfl_xor(val, 8);
        if (ti == 0) partial[bx * NLAB + l] = val;
    }
}

// Dispatch 2: one block, 256 threads. Reduce 1024x16 partials (coalesced,
// L2-resident), count n_pos per label, apply dynamic weights, write scalar.
__global__ __launch_bounds__(256) void auc_reduce(const int* __restrict__ yt,
                                                  const float* __restrict__ partial,
                                                  float* __restrict__ out) {
    __shared__ float lsum[16][NLAB];
    __shared__ int   lcnt[16][NLAB];
    __shared__ float pl_s[NLAB];
    __shared__ int   pl_c[NLAB];

    const int t = threadIdx.x;
    const int lab = t & 15;
    const int grp = t >> 4;   // 0..15

    // Thread t sums slots (grp+16k)*16+lab == t + 256k: fully coalesced.
    float s = 0.0f;
    #pragma unroll 16
    for (int k = 0; k < NBLK / 16; ++k) {
        s += partial[t + 256 * k];
    }
    lsum[grp][lab] = s;

    int cnt = 0;
    #pragma unroll 8
    for (int k = 0; k < NROWS / 16; ++k) {
        cnt += (yt[(grp + 16 * k) * NLAB + lab] == 1) ? 1 : 0;
    }
    lcnt[grp][lab] = cnt;
    __syncthreads();

    if (t < NLAB) {
        float ps = 0.0f;
        int pc = 0;
        #pragma unroll
        for (int g = 0; g < 16; ++g) {
            ps += lsum[g][t];
            pc += lcnt[g][t];
        }
        pl_s[t] = ps;
        pl_c[t] = pc;
    }
    __syncthreads();

    if (t == 0) {
        double loss = 0.0;
        #pragma unroll
        for (int l = 0; l < NLAB; ++l) {
            const int np_ = pl_c[l];
            const int nn_ = NROWS - np_;   // mn = 1 - mp
            if (np_ > 0 && nn_ > 0) {
                const double prod = (double)np_ * (double)nn_;
                const double denom = prod * prod * (double)(NLAB * NLAB);
                loss += (double)pl_s[l] / denom;
            }
        }
        out[0] = (float)loss;
    }
}

extern "C" void kernel_launch(void* const* d_in, const int* in_sizes, int n_in,
                              void* d_out, int out_size, void* d_ws, size_t ws_size,
                              hipStream_t stream) {
    const int* y_true = (const int*)d_in[0];
    const float* y_pred = (const float*)d_in[1];
    float* out = (float*)d_out;
    float* partial = (float*)d_ws;   // NBLK*NLAB floats = 64 KB

    auc_pair<<<NBLK, 256, 0, stream>>>(y_true, y_pred, partial);
    auc_reduce<<<1, 256, 0, stream>>>(y_true, partial, out);
}